// Round 2
// baseline (2276.124 us; speedup 1.0000x reference)
//
#include <hip/hip_runtime.h>
#include <hip/hip_bf16.h>
#include <math.h>

// GPT-2 block: B=4 S=2048 E=2048 H=16 HD=128 M=8192.
// bf16 MFMA (16x16x32), fp32 accumulate. Causal mask hard-coded.
// R1: workspace cut 480MB -> 224MB (suspected ws overflow fault):
//   x1 lives in d_out; h2 shares h; q/k/v/attn per-batch; scores per 8-head
//   group; FC/Wp chunked over M (4 slices) accumulating into d_out.

typedef __bf16 bf16;
typedef __attribute__((ext_vector_type(8))) __bf16 bf16x8;
typedef __attribute__((ext_vector_type(4))) float f32x4;

#define GLOBAL_AS __attribute__((address_space(1)))
#define LDS_AS __attribute__((address_space(3)))

__device__ __forceinline__ void gl_lds16(const bf16* g, bf16* l) {
  __builtin_amdgcn_global_load_lds((const GLOBAL_AS void*)g, (LDS_AS void*)l, 16, 0, 0);
}

struct Acc { f32x4 v[4][4]; };

// 128x128 tile at (m0,n0). A: MxK row-major (lda). Bt: NxK row-major (ldb).
// 256 thr = 4 waves 2x2, each a 64x64 quadrant. K in 32-steps.
__device__ __forceinline__ void gemm_core(const bf16* __restrict__ A, long lda,
                                          const bf16* __restrict__ Bt, long ldb,
                                          int m0, int n0, int kbeg, int kend,
                                          bf16* sa, bf16* sb, Acc& acc) {
  const int t    = threadIdx.x;
  const int lane = t & 63;
  const int w    = t >> 6;
  const int wm   = (w >> 1) << 6;
  const int wn   = (w & 1) << 6;
  const int quad = lane >> 4;
  const int l15  = lane & 15;
  const int rowA = t >> 2;        // staging row 0..63
  const int kc   = (t & 3) << 3;  // staging col offset (8 elems)

#pragma unroll
  for (int i = 0; i < 4; i++)
#pragma unroll
    for (int j = 0; j < 4; j++)
      acc.v[i][j] = f32x4{0.f, 0.f, 0.f, 0.f};

  bf16* sa_w0 = &sa[(w << 6) * 8];
  bf16* sa_w1 = &sa[(256 + (w << 6)) * 8];
  bf16* sb_w0 = &sb[(w << 6) * 8];
  bf16* sb_w1 = &sb[(256 + (w << 6)) * 8];

  for (int k0 = kbeg; k0 < kend; k0 += 32) {
    const bf16* ga = A + (long)(m0 + rowA) * lda + (k0 + kc);
    const bf16* gb = Bt + (long)(n0 + rowA) * ldb + (k0 + kc);
    gl_lds16(ga, sa_w0);
    gl_lds16(ga + 64 * lda, sa_w1);
    gl_lds16(gb, sb_w0);
    gl_lds16(gb + 64 * ldb, sb_w1);
    __syncthreads();

    bf16x8 af[4], bfv[4];
#pragma unroll
    for (int i = 0; i < 4; i++)
      af[i] = *(const bf16x8*)&sa[(wm + i * 16 + l15) * 32 + quad * 8];
#pragma unroll
    for (int j = 0; j < 4; j++)
      bfv[j] = *(const bf16x8*)&sb[(wn + j * 16 + l15) * 32 + quad * 8];
#pragma unroll
    for (int i = 0; i < 4; i++)
#pragma unroll
      for (int j = 0; j < 4; j++)
        acc.v[i][j] = __builtin_amdgcn_mfma_f32_16x16x32_bf16(af[i], bfv[j], acc.v[i][j], 0, 0, 0);
    __syncthreads();
  }
}

// C/D: lane l, reg r -> row=(l>>4)*4+r, col=l&15
template <typename F>
__device__ __forceinline__ void epilogue(int m0, int n0, const Acc& acc, F f) {
  const int t = threadIdx.x;
  const int lane = t & 63;
  const int w = t >> 6;
  const int wm = (w >> 1) << 6, wn = (w & 1) << 6;
  const int quad = lane >> 4, l15 = lane & 15;
#pragma unroll
  for (int i = 0; i < 4; i++)
#pragma unroll
    for (int j = 0; j < 4; j++)
#pragma unroll
      for (int r = 0; r < 4; r++)
        f(m0 + wm + i * 16 + quad * 4 + r, n0 + wn + j * 16 + l15, acc.v[i][j][r]);
}

// -------- weight convert+transpose: src[R][C] fp32 -> dst[C][R] bf16 --------
__global__ void k_transpose_cast(const float* __restrict__ src, bf16* __restrict__ dst,
                                 int R, int C) {
  __shared__ float tile[32][33];
  const int c0 = blockIdx.x << 5, r0 = blockIdx.y << 5;
  const int tx = threadIdx.x, ty = threadIdx.y;
  for (int i = ty; i < 32; i += 8)
    tile[i][tx] = src[(long)(r0 + i) * C + (c0 + tx)];
  __syncthreads();
  for (int i = ty; i < 32; i += 8)
    dst[(long)(c0 + i) * R + (r0 + tx)] = (bf16)tile[tx][i];
}

// -------- layernorm over E=2048, fp32 in, bf16 out --------
__global__ void k_layernorm(const float* __restrict__ x, const float* __restrict__ g,
                            const float* __restrict__ bta, bf16* __restrict__ out) {
  __shared__ float red[8];
  const long row = blockIdx.x;
  const float* xr = x + row * 2048;
  const int t = threadIdx.x;
  float4 a = reinterpret_cast<const float4*>(xr)[t];
  float4 b4 = reinterpret_cast<const float4*>(xr)[t + 256];
  float va[8] = {a.x, a.y, a.z, a.w, b4.x, b4.y, b4.z, b4.w};
  float s = 0.f, ss = 0.f;
#pragma unroll
  for (int i = 0; i < 8; i++) { s += va[i]; ss += va[i] * va[i]; }
#pragma unroll
  for (int o = 32; o > 0; o >>= 1) { s += __shfl_xor(s, o, 64); ss += __shfl_xor(ss, o, 64); }
  if ((t & 63) == 0) { red[t >> 6] = s; red[4 + (t >> 6)] = ss; }
  __syncthreads();
  s = red[0] + red[1] + red[2] + red[3];
  ss = red[4] + red[5] + red[6] + red[7];
  const float mu = s * (1.f / 2048.f);
  const float rstd = rsqrtf(ss * (1.f / 2048.f) - mu * mu + 1e-5f);
  bf16* op = out + row * 2048;
#pragma unroll
  for (int c = 0; c < 4; c++) {
    int i0 = t * 4 + c;
    op[i0] = (bf16)((va[c] - mu) * rstd * g[i0] + bta[i0]);
    int i1 = 1024 + t * 4 + c;
    op[i1] = (bf16)((va[4 + c] - mu) * rstd * g[i1] + bta[i1]);
  }
}

// -------- QKV per batch: h_b[2048][2048] x WqkvT[6144][2048]^T --------
// q,k -> [H][S][D] (q scaled); v -> [H][D][S]
__global__ __launch_bounds__(256, 2) void k_gemm_qkv(
    const bf16* __restrict__ A, const bf16* __restrict__ Bt, const float* __restrict__ bias,
    bf16* __restrict__ q, bf16* __restrict__ k, bf16* __restrict__ v) {
  __shared__ bf16 sa[128 * 32], sb[128 * 32];
  const int m0 = blockIdx.y << 7, n0 = blockIdx.x << 7;
  Acc acc;
  gemm_core(A, 2048, Bt, 2048, m0, n0, 0, 2048, sa, sb, acc);
  epilogue(m0, n0, acc, [&](int row, int col, float val) {
    float vv = val + bias[col];
    const int which = col >> 11, hh = (col >> 7) & 15, d = col & 127;
    if (which == 0)
      q[((long)hh * 2048 + row) * 128 + d] = (bf16)(vv * 0.08838834764831845f);
    else if (which == 1)
      k[((long)hh * 2048 + row) * 128 + d] = (bf16)vv;
    else
      v[((long)hh * 128 + d) * 2048 + row] = (bf16)vv;
  });
}

// -------- scores for 8-head group g: q x k^T, causal tiles only --------
__global__ __launch_bounds__(256, 2) void k_gemm_scores(
    const bf16* __restrict__ q, const bf16* __restrict__ kk, bf16* __restrict__ sc, int g) {
  const int m0 = blockIdx.y << 7, n0 = blockIdx.x << 7;
  if (n0 > m0) return;
  const int hp = blockIdx.z;  // 0..7
  __shared__ bf16 sa[128 * 32], sb[128 * 32];
  const bf16* qb = q + (long)(g * 8 + hp) * 2048 * 128;
  const bf16* kb = kk + (long)(g * 8 + hp) * 2048 * 128;
  Acc acc;
  gemm_core(qb, 128, kb, 128, m0, n0, 0, 128, sa, sb, acc);
  bf16* scp = sc + (long)hp * 2048 * 2048;
  epilogue(m0, n0, acc, [&](int row, int col, float val) {
    scp[(long)row * 2048 + col] = (bf16)val;
  });
}

// -------- causal softmax per row, zero-pad to next 128 --------
__global__ void k_softmax(bf16* __restrict__ sc) {
  __shared__ float red[8];
  const int sq = blockIdx.x, hp = blockIdx.y;
  bf16* rowp = sc + ((long)hp * 2048 + sq) * 2048;
  const int L = sq + 1;
  const int Lpad = ((sq >> 7) + 1) << 7;
  const int t = threadIdx.x;
  float v[8];
  float mx = -3e38f;
#pragma unroll
  for (int i = 0; i < 8; i++) {
    int idx = t + (i << 8);
    v[i] = (idx < L) ? (float)rowp[idx] : -3e38f;
    mx = fmaxf(mx, v[i]);
  }
#pragma unroll
  for (int o = 32; o > 0; o >>= 1) mx = fmaxf(mx, __shfl_xor(mx, o, 64));
  if ((t & 63) == 0) red[t >> 6] = mx;
  __syncthreads();
  mx = fmaxf(fmaxf(red[0], red[1]), fmaxf(red[2], red[3]));
  float sum = 0.f;
#pragma unroll
  for (int i = 0; i < 8; i++) {
    int idx = t + (i << 8);
    if (idx < L) { v[i] = __expf(v[i] - mx); sum += v[i]; }
  }
#pragma unroll
  for (int o = 32; o > 0; o >>= 1) sum += __shfl_xor(sum, o, 64);
  if ((t & 63) == 0) red[4 + (t >> 6)] = sum;
  __syncthreads();
  sum = red[4] + red[5] + red[6] + red[7];
  const float inv = 1.f / sum;
#pragma unroll
  for (int i = 0; i < 8; i++) {
    int idx = t + (i << 8);
    if (idx < L) rowp[idx] = (bf16)(v[i] * inv);
    else if (idx < Lpad) rowp[idx] = (bf16)0.f;
  }
}

// -------- PV for head group g: P x vT^T, K truncated at diagonal --------
__global__ __launch_bounds__(256, 2) void k_gemm_pv(
    const bf16* __restrict__ sc, const bf16* __restrict__ v, bf16* __restrict__ attn, int g) {
  __shared__ bf16 sa[128 * 32], sb[128 * 32];
  const int m0 = blockIdx.x << 7;
  const int hp = blockIdx.y;
  const bf16* A = sc + (long)hp * 2048 * 2048;
  const bf16* Bt = v + (long)(g * 8 + hp) * 128 * 2048;
  Acc acc;
  gemm_core(A, 2048, Bt, 2048, m0, 0, 0, m0 + 128, sa, sb, acc);
  epilogue(m0, 0, acc, [&](int row, int col, float val) {
    attn[((long)row * 16 + (g * 8 + hp)) * 128 + col] = (bf16)val;
  });
}

// -------- Wo proj + residual -> x1 (= d_out slice) --------
__global__ __launch_bounds__(256, 2) void k_gemm_wo(
    const bf16* __restrict__ A, const bf16* __restrict__ Bt, const float* __restrict__ bias,
    const float* __restrict__ xin, float* __restrict__ x1) {
  __shared__ bf16 sa[128 * 32], sb[128 * 32];
  const int m0 = blockIdx.y << 7, n0 = blockIdx.x << 7;
  Acc acc;
  gemm_core(A, 2048, Bt, 2048, m0, n0, 0, 2048, sa, sb, acc);
  epilogue(m0, n0, acc, [&](int row, int col, float val) {
    long idx = (long)row * 2048 + col;
    x1[idx] = xin[idx] + val + bias[col];
  });
}

// -------- FC chunk c: h2 x WfcT[c*2048..+2048)^T + gelu -> ff[8192][2048] --------
__global__ __launch_bounds__(256, 2) void k_gemm_fc(
    const bf16* __restrict__ A, const bf16* __restrict__ Bt, const float* __restrict__ bias,
    bf16* __restrict__ ff, int c) {
  __shared__ bf16 sa[128 * 32], sb[128 * 32];
  const int m0 = blockIdx.y << 7, n0 = blockIdx.x << 7;
  Acc acc;
  gemm_core(A, 2048, Bt, 2048, m0, n0, 0, 2048, sa, sb, acc);
  epilogue(m0, n0, acc, [&](int row, int col, float val) {
    float u = val + bias[c * 2048 + col];
    float cc = 0.7978845608028654f * (u + 0.044715f * u * u * u);
    float ge = 0.5f * u * (1.f + tanhf(cc));
    ff[(long)row * 2048 + col] = (bf16)ge;
  });
}

// -------- Wp chunk c: ff[8192][2048] x WpT[:, c*2048..)^T accumulate into out --------
__global__ __launch_bounds__(256, 2) void k_gemm_wp(
    const bf16* __restrict__ A, const bf16* __restrict__ Bt, const float* __restrict__ bias,
    float* __restrict__ out, int addbias) {
  __shared__ bf16 sa[128 * 32], sb[128 * 32];
  const int m0 = blockIdx.y << 7, n0 = blockIdx.x << 7;
  Acc acc;
  gemm_core(A, 2048, Bt, 8192, m0, n0, 0, 2048, sa, sb, acc);
  epilogue(m0, n0, acc, [&](int row, int col, float val) {
    long idx = (long)row * 2048 + col;
    float b = addbias ? bias[col] : 0.f;
    out[idx] = out[idx] + val + b;
  });
}

extern "C" void kernel_launch(void* const* d_in, const int* in_sizes, int n_in,
                              void* d_out, int out_size, void* d_ws, size_t ws_size,
                              hipStream_t stream) {
  const float* x     = (const float*)d_in[0];
  const float* ln1_g = (const float*)d_in[2];
  const float* ln1_b = (const float*)d_in[3];
  const float* Wqkv  = (const float*)d_in[4];
  const float* bqkv  = (const float*)d_in[5];
  const float* Wo    = (const float*)d_in[6];
  const float* bo    = (const float*)d_in[7];
  const float* ln2_g = (const float*)d_in[8];
  const float* ln2_b = (const float*)d_in[9];
  const float* Wfc   = (const float*)d_in[10];
  const float* bfc   = (const float*)d_in[11];
  const float* Wp    = (const float*)d_in[12];
  const float* bp    = (const float*)d_in[13];
  float* out = (float*)d_out;

  // workspace layout: 224 MiB total
  char* p = (char*)d_ws;
  bf16* WqkvT = (bf16*)p; p += 6144L * 2048 * 2;   //  25.2 MB
  bf16* WoT   = (bf16*)p; p += 2048L * 2048 * 2;   //   8.4 MB
  bf16* WfcT  = (bf16*)p; p += 8192L * 2048 * 2;   //  33.6 MB
  bf16* WpT   = (bf16*)p; p += 2048L * 8192 * 2;   //  33.6 MB
  bf16* h     = (bf16*)p; p += 8192L * 2048 * 2;   //  33.6 MB (h2 shares)
  bf16* qb    = (bf16*)p; p += 16L * 2048 * 128 * 2;  // 8.4 MB per-batch
  bf16* kb    = (bf16*)p; p += 16L * 2048 * 128 * 2;
  bf16* vb    = (bf16*)p; p += 16L * 2048 * 128 * 2;
  bf16* attnb = (bf16*)p; p += 16L * 2048 * 128 * 2;
  bf16* sc    = (bf16*)p; p += 8L * 2048 * 2048 * 2;  // 67.1 MB (ff chunk shares)
  bf16* h2 = h;
  bf16* ff = sc;

  dim3 tb(32, 8);
  k_transpose_cast<<<dim3(192, 64), tb, 0, stream>>>(Wqkv, WqkvT, 2048, 6144);
  k_transpose_cast<<<dim3(64, 64), tb, 0, stream>>>(Wo, WoT, 2048, 2048);
  k_transpose_cast<<<dim3(256, 64), tb, 0, stream>>>(Wfc, WfcT, 2048, 8192);
  k_transpose_cast<<<dim3(64, 256), tb, 0, stream>>>(Wp, WpT, 8192, 2048);

  k_layernorm<<<8192, 256, 0, stream>>>(x, ln1_g, ln1_b, h);

  for (int b = 0; b < 4; b++) {
    const bf16* hb = h + (long)b * 2048 * 2048;
    k_gemm_qkv<<<dim3(48, 16), 256, 0, stream>>>(hb, WqkvT, bqkv, qb, kb, vb);
    for (int g = 0; g < 2; g++) {
      k_gemm_scores<<<dim3(16, 16, 8), 256, 0, stream>>>(qb, kb, sc, g);
      k_softmax<<<dim3(2048, 8), 256, 0, stream>>>(sc);
      k_gemm_pv<<<dim3(16, 8), 256, 0, stream>>>(sc, vb, attnb, g);
    }
    k_gemm_wo<<<dim3(16, 16), 256, 0, stream>>>(attnb, WoT, bo,
                                                x + (long)b * 2048 * 2048,
                                                out + (long)b * 2048 * 2048);
  }

  k_layernorm<<<8192, 256, 0, stream>>>(out, ln2_g, ln2_b, h2);

  for (int c = 0; c < 4; c++) {
    k_gemm_fc<<<dim3(16, 64), 256, 0, stream>>>(h2, WfcT + (long)c * 2048 * 2048, bfc, ff, c);
    k_gemm_wp<<<dim3(16, 64), 256, 0, stream>>>(ff, WpT + (long)c * 2048, bp, out, c == 0);
  }
}